// Round 14
// baseline (284.786 us; speedup 1.0000x reference)
//
#include <hip/hip_runtime.h>
#include <hip/hip_bf16.h>
#include <stdint.h>

#define R_ 8
#define N_ 8192
#define D_ 2048
#define A_ 128
#define J_ 1024          // R_*A_
#define LN_EPS 1e-5f

typedef __attribute__((ext_vector_type(8))) short bf16x8;   // 8 bf16 in 4 VGPRs
typedef __attribute__((ext_vector_type(4))) float f32x4;

__device__ inline ushort f2bf(float f) {
    union { float f; uint32_t u; } v; v.f = f;
    uint32_t u = v.u;
    return (ushort)((u + 0x7fffu + ((u >> 16) & 1u)) >> 16);   // RNE
}
__device__ inline float bf2f(ushort u) {
    union { uint32_t u; float f; } v; v.u = ((uint32_t)u) << 16;
    return v.f;
}

// ---------------------------------------------------------------------------
// k_prep: blocks [0,N_)   : row-LN stats of x -> xhat bf16 (shared by routers)
//         blocks [N_,N_+J_): weight-LN column j -> Bt bf16 (K-major) + cvec
// ---------------------------------------------------------------------------
__global__ __launch_bounds__(256) void k_prep(
    const float* __restrict__ x,
    const float* __restrict__ W,
    const float* __restrict__ ln_w,
    const float* __restrict__ ln_b,
    const float* __restrict__ rw_w,
    const float* __restrict__ rw_b,
    const float* __restrict__ rbias,
    ushort* __restrict__ xhat,
    ushort* __restrict__ Bt,
    float* __restrict__ cvec)
{
    __shared__ float sm[16];
    const int t = threadIdx.x;

    if (blockIdx.x < N_) {
        const int n = blockIdx.x;
        const float* xr = x + (size_t)n * D_;
        float4 v0 = *(const float4*)(xr + t * 4);
        float4 v1 = *(const float4*)(xr + 1024 + t * 4);
        float s  = v0.x + v0.y + v0.z + v0.w + v1.x + v1.y + v1.z + v1.w;
        float sq = v0.x*v0.x + v0.y*v0.y + v0.z*v0.z + v0.w*v0.w
                 + v1.x*v1.x + v1.y*v1.y + v1.z*v1.z + v1.w*v1.w;
        #pragma unroll
        for (int o = 32; o > 0; o >>= 1) {
            s  += __shfl_xor(s,  o, 64);
            sq += __shfl_xor(sq, o, 64);
        }
        if ((t & 63) == 0) { sm[t >> 6] = s; sm[8 + (t >> 6)] = sq; }
        __syncthreads();
        s  = sm[0] + sm[1] + sm[2] + sm[3];
        sq = sm[8] + sm[9] + sm[10] + sm[11];
        const float mean = s * (1.0f / D_);
        const float var  = sq * (1.0f / D_) - mean * mean;
        const float rstd = rsqrtf(var + LN_EPS);

        ushort4 p0 = make_ushort4(f2bf((v0.x - mean) * rstd), f2bf((v0.y - mean) * rstd),
                                  f2bf((v0.z - mean) * rstd), f2bf((v0.w - mean) * rstd));
        ushort4 p1 = make_ushort4(f2bf((v1.x - mean) * rstd), f2bf((v1.y - mean) * rstd),
                                  f2bf((v1.z - mean) * rstd), f2bf((v1.w - mean) * rstd));
        *(ushort4*)(xhat + (size_t)n * D_ + t * 4)        = p0;
        *(ushort4*)(xhat + (size_t)n * D_ + 1024 + t * 4) = p1;
    } else {
        const int j = blockIdx.x - N_;
        const int r = j >> 7, a = j & 127;
        const float* Wc = W + (size_t)r * D_ * A_ + a;

        float vals[8];
        float s = 0.f, sq = 0.f;
        #pragma unroll
        for (int k = 0; k < 8; ++k) {
            float v = Wc[(size_t)(t + k * 256) * A_];
            vals[k] = v; s += v; sq += v * v;
        }
        #pragma unroll
        for (int o = 32; o > 0; o >>= 1) {
            s  += __shfl_xor(s,  o, 64);
            sq += __shfl_xor(sq, o, 64);
        }
        if ((t & 63) == 0) { sm[t >> 6] = s; sm[8 + (t >> 6)] = sq; }
        __syncthreads();
        s  = sm[0] + sm[1] + sm[2] + sm[3];
        sq = sm[8] + sm[9] + sm[10] + sm[11];
        const float mean = s * (1.0f / D_);
        const float var  = sq * (1.0f / D_) - mean * mean;
        const float rstd = rsqrtf(var + LN_EPS);

        float cp = 0.f;
        #pragma unroll
        for (int k = 0; k < 8; ++k) {
            const int d = t + k * 256;
            const float nv = (vals[k] - mean) * rstd * rw_w[(size_t)r * D_ + d]
                           + rw_b[(size_t)r * D_ + d];
            Bt[(size_t)j * D_ + d] = f2bf(ln_w[(size_t)r * D_ + d] * nv);
            cp += ln_b[(size_t)r * D_ + d] * nv;
        }
        __syncthreads();   // sm reuse
        #pragma unroll
        for (int o = 32; o > 0; o >>= 1) cp += __shfl_xor(cp, o, 64);
        if ((t & 63) == 0) sm[t >> 6] = cp;
        __syncthreads();
        if (t == 0) cvec[j] = sm[0] + sm[1] + sm[2] + sm[3] + rbias[(size_t)r * A_ + a];
    }
}

// ---------------------------------------------------------------------------
// k_fused (R14): R13's phase-staggered structure with the STAGGER BIT FIXED.
//   Per-CU resident blocks are bids {c, c+256, c+512, c+768} -> mt =
//   {c', c'+32, c'+64, c'+96}. R13 keyed the phase order on mt&1 (identical
//   for all four -> phases serialized per CU: 275 us, the accidental serial
//   measurement). R14 keys on (mt>>5)&1 -> pattern {0,1,0,1}: each CU always
//   hosts ~2 pure-GEMM blocks and ~2 pure-WRITE blocks with zero shared
//   sync — the true test of decoupled-stream overlap.
// ---------------------------------------------------------------------------
__global__ __launch_bounds__(256) void k_fused(
    const ushort* __restrict__ Xh,
    const ushort* __restrict__ Bt,
    const float* __restrict__ cvec,
    const float* __restrict__ ln_w,
    const float* __restrict__ ln_b,
    float* __restrict__ new_x,
    float* __restrict__ logits,
    float* __restrict__ probs)
{
    __shared__ __attribute__((aligned(16))) ushort As[64 * 32];    // 4 KB
    __shared__ __attribute__((aligned(16))) ushort Bs[128 * 32];   // 8 KB

    const int t    = threadIdx.x;
    const int lane = t & 63;
    const int w    = t >> 6;             // wave 0..3
    const int r    = blockIdx.x & 7;     // router == XCD
    const int mt   = blockIdx.x >> 3;    // m-tile 0..127
    const int m0   = mt * 64;
    const int j0   = r * 128;

    // thread t's fixed output columns: 8t..8t+7 — LN params in registers
    const float4 lwa = *(const float4*)(ln_w + (size_t)r * D_ + t * 8);
    const float4 lwb = *(const float4*)(ln_w + (size_t)r * D_ + t * 8 + 4);
    const float4 lba = *(const float4*)(ln_b + (size_t)r * D_ + t * 8);
    const float4 lbb = *(const float4*)(ln_b + (size_t)r * D_ + t * 8 + 4);

    float* nx_base = new_x + ((size_t)r * N_ + m0) * D_;

    // -------- WRITE phase: pure contiguous NT fill of the 512 KiB slab ----
    auto write_phase = [&]() {
        const ushort* xs = Xh + (size_t)m0 * D_ + t * 8;
        float* nd = nx_base + t * 8;
        #pragma unroll 4
        for (int i = 0; i < 64; ++i) {
            const bf16x8 h = *(const bf16x8*)(xs + (size_t)i * D_);
            f32x4 o0, o1;
            o0[0] = bf2f((ushort)h[0]) * lwa.x + lba.x;
            o0[1] = bf2f((ushort)h[1]) * lwa.y + lba.y;
            o0[2] = bf2f((ushort)h[2]) * lwa.z + lba.z;
            o0[3] = bf2f((ushort)h[3]) * lwa.w + lba.w;
            o1[0] = bf2f((ushort)h[4]) * lwb.x + lbb.x;
            o1[1] = bf2f((ushort)h[5]) * lwb.y + lbb.y;
            o1[2] = bf2f((ushort)h[6]) * lwb.z + lbb.z;
            o1[3] = bf2f((ushort)h[7]) * lwb.w + lbb.w;
            __builtin_nontemporal_store(o0, (f32x4*)(nd + (size_t)i * D_));
            __builtin_nontemporal_store(o1, (f32x4*)(nd + (size_t)i * D_ + 4));
        }
    };

    // -------- GEMM phase: R7's proven loop + fused softmax ----------------
    auto gemm_phase = [&]() {
        f32x4 acc[8];
        #pragma unroll
        for (int jf = 0; jf < 8; ++jf) acc[jf] = (f32x4){0.f, 0.f, 0.f, 0.f};

        for (int kt = 0; kt < 64; ++kt) {
            __syncthreads();                 // prev iter's LDS reads done
            {
                const int row = t >> 2;      // 0..63
                const int kc  = t & 3;
                const ushort* gA = Xh + (size_t)(m0 + row) * D_ + kt * 32 + kc * 8;
                __builtin_amdgcn_global_load_lds(
                    (const __attribute__((address_space(1))) void*)gA,
                    (__attribute__((address_space(3))) void*)(&As[t * 8]), 16, 0, 0);
            }
            #pragma unroll
            for (int c = 0; c < 2; ++c) {
                const int q   = t + c * 256;
                const int row = q >> 2;      // 0..127
                const int kc  = q & 3;
                const ushort* gB = Bt + (size_t)(j0 + row) * D_ + kt * 32 + kc * 8;
                __builtin_amdgcn_global_load_lds(
                    (const __attribute__((address_space(1))) void*)gB,
                    (__attribute__((address_space(3))) void*)(&Bs[q * 8]), 16, 0, 0);
            }
            __syncthreads();                 // staging complete

            const bf16x8 afr = *(const bf16x8*)(&As[(w * 16 + (lane & 15)) * 32
                                                    + (lane >> 4) * 8]);
            #pragma unroll
            for (int jf = 0; jf < 8; ++jf) {
                const bf16x8 bfr = *(const bf16x8*)(&Bs[(jf * 16 + (lane & 15)) * 32
                                                        + (lane >> 4) * 8]);
                acc[jf] = __builtin_amdgcn_mfma_f32_16x16x32_bf16(afr, bfr, acc[jf], 0, 0, 0);
            }
        }

        // Epilogue: bias + row softmax. C/D: col=lane&15, row=(lane>>4)*4+reg.
        float cv[8];
        #pragma unroll
        for (int jf = 0; jf < 8; ++jf) cv[jf] = cvec[j0 + jf * 16 + (lane & 15)];

        #pragma unroll
        for (int reg = 0; reg < 4; ++reg) {
            const int row = m0 + w * 16 + (lane >> 4) * 4 + reg;
            float v[8], e[8];
            float mx = -3.4e38f;
            #pragma unroll
            for (int jf = 0; jf < 8; ++jf) {
                v[jf] = acc[jf][reg] + cv[jf];
                mx = fmaxf(mx, v[jf]);
            }
            #pragma unroll
            for (int o = 8; o > 0; o >>= 1) mx = fmaxf(mx, __shfl_xor(mx, o, 64));
            float ssum = 0.f;
            #pragma unroll
            for (int jf = 0; jf < 8; ++jf) { e[jf] = __expf(v[jf] - mx); ssum += e[jf]; }
            #pragma unroll
            for (int o = 8; o > 0; o >>= 1) ssum += __shfl_xor(ssum, o, 64);
            const float inv = 1.0f / ssum;
            float* lrow = logits + ((size_t)r * N_ + row) * A_;
            float* prow = probs  + ((size_t)r * N_ + row) * A_;
            #pragma unroll
            for (int jf = 0; jf < 8; ++jf) {
                const int aa = jf * 16 + (lane & 15);
                __builtin_nontemporal_store(v[jf], lrow + aa);
                __builtin_nontemporal_store(e[jf] * inv, prow + aa);
            }
        }
    };

    // per-CU resident mt values are {c, c+32, c+64, c+96} -> bit 5 alternates
    if ((mt >> 5) & 1) { write_phase(); gemm_phase(); }
    else               { gemm_phase(); write_phase(); }
}

// ---------------------------------------------------------------------------
extern "C" void kernel_launch(void* const* d_in, const int* in_sizes, int n_in,
                              void* d_out, int out_size, void* d_ws, size_t ws_size,
                              hipStream_t stream)
{
    const float* x     = (const float*)d_in[0];
    const float* ln_w  = (const float*)d_in[1];
    const float* ln_b  = (const float*)d_in[2];
    const float* W     = (const float*)d_in[3];
    const float* rw_w  = (const float*)d_in[4];
    const float* rw_b  = (const float*)d_in[5];
    const float* rbias = (const float*)d_in[6];

    float* out    = (float*)d_out;
    float* new_x  = out;                                   // [R,N,D]
    float* logits = out + (size_t)R_ * N_ * D_;            // [R,N,A]
    float* probs  = logits + (size_t)R_ * N_ * A_;         // [R,N,A]

    // ws: xhat bf16 [N][D] (32 MiB) | Bt bf16 [J][D] (4 MiB) | cvec f32 [J]
    ushort* xhat = (ushort*)d_ws;
    ushort* Btp  = (ushort*)((char*)d_ws + (size_t)N_ * D_ * 2);
    float*  cvec = (float*)((char*)d_ws + (size_t)N_ * D_ * 2 + (size_t)J_ * D_ * 2);

    hipLaunchKernelGGL(k_prep, dim3(N_ + J_), dim3(256), 0, stream,
                       x, W, ln_w, ln_b, rw_w, rw_b, rbias, xhat, Btp, cvec);
    hipLaunchKernelGGL(k_fused, dim3(J_), dim3(256), 0, stream,
                       xhat, Btp, cvec, ln_w, ln_b, new_x, logits, probs);
}

// Round 15
// 182.835 us; speedup vs baseline: 1.5576x; 1.5576x over previous
//
#include <hip/hip_runtime.h>
#include <hip/hip_bf16.h>
#include <stdint.h>

#define R_ 8
#define N_ 8192
#define D_ 2048
#define A_ 128
#define J_ 1024          // R_*A_
#define LN_EPS 1e-5f

typedef __attribute__((ext_vector_type(8))) short bf16x8;   // 8 bf16 in 4 VGPRs
typedef __attribute__((ext_vector_type(4))) float f32x4;

__device__ inline ushort f2bf(float f) {
    union { float f; uint32_t u; } v; v.f = f;
    uint32_t u = v.u;
    return (ushort)((u + 0x7fffu + ((u >> 16) & 1u)) >> 16);   // RNE
}
__device__ inline float bf2f(ushort u) {
    union { uint32_t u; float f; } v; v.u = ((uint32_t)u) << 16;
    return v.f;
}

// ---------------------------------------------------------------------------
// k_prep: blocks [0,N_)   : row-LN stats of x -> xhat bf16 (shared by routers)
//         blocks [N_,N_+J_): weight-LN column j -> Bt bf16 (K-major) + cvec
// ---------------------------------------------------------------------------
__global__ __launch_bounds__(256) void k_prep(
    const float* __restrict__ x,
    const float* __restrict__ W,
    const float* __restrict__ ln_w,
    const float* __restrict__ ln_b,
    const float* __restrict__ rw_w,
    const float* __restrict__ rw_b,
    const float* __restrict__ rbias,
    ushort* __restrict__ xhat,
    ushort* __restrict__ Bt,
    float* __restrict__ cvec)
{
    __shared__ float sm[16];
    const int t = threadIdx.x;

    if (blockIdx.x < N_) {
        const int n = blockIdx.x;
        const float* xr = x + (size_t)n * D_;
        float4 v0 = *(const float4*)(xr + t * 4);
        float4 v1 = *(const float4*)(xr + 1024 + t * 4);
        float s  = v0.x + v0.y + v0.z + v0.w + v1.x + v1.y + v1.z + v1.w;
        float sq = v0.x*v0.x + v0.y*v0.y + v0.z*v0.z + v0.w*v0.w
                 + v1.x*v1.x + v1.y*v1.y + v1.z*v1.z + v1.w*v1.w;
        #pragma unroll
        for (int o = 32; o > 0; o >>= 1) {
            s  += __shfl_xor(s,  o, 64);
            sq += __shfl_xor(sq, o, 64);
        }
        if ((t & 63) == 0) { sm[t >> 6] = s; sm[8 + (t >> 6)] = sq; }
        __syncthreads();
        s  = sm[0] + sm[1] + sm[2] + sm[3];
        sq = sm[8] + sm[9] + sm[10] + sm[11];
        const float mean = s * (1.0f / D_);
        const float var  = sq * (1.0f / D_) - mean * mean;
        const float rstd = rsqrtf(var + LN_EPS);

        ushort4 p0 = make_ushort4(f2bf((v0.x - mean) * rstd), f2bf((v0.y - mean) * rstd),
                                  f2bf((v0.z - mean) * rstd), f2bf((v0.w - mean) * rstd));
        ushort4 p1 = make_ushort4(f2bf((v1.x - mean) * rstd), f2bf((v1.y - mean) * rstd),
                                  f2bf((v1.z - mean) * rstd), f2bf((v1.w - mean) * rstd));
        *(ushort4*)(xhat + (size_t)n * D_ + t * 4)        = p0;
        *(ushort4*)(xhat + (size_t)n * D_ + 1024 + t * 4) = p1;
    } else {
        const int j = blockIdx.x - N_;
        const int r = j >> 7, a = j & 127;
        const float* Wc = W + (size_t)r * D_ * A_ + a;

        float vals[8];
        float s = 0.f, sq = 0.f;
        #pragma unroll
        for (int k = 0; k < 8; ++k) {
            float v = Wc[(size_t)(t + k * 256) * A_];
            vals[k] = v; s += v; sq += v * v;
        }
        #pragma unroll
        for (int o = 32; o > 0; o >>= 1) {
            s  += __shfl_xor(s,  o, 64);
            sq += __shfl_xor(sq, o, 64);
        }
        if ((t & 63) == 0) { sm[t >> 6] = s; sm[8 + (t >> 6)] = sq; }
        __syncthreads();
        s  = sm[0] + sm[1] + sm[2] + sm[3];
        sq = sm[8] + sm[9] + sm[10] + sm[11];
        const float mean = s * (1.0f / D_);
        const float var  = sq * (1.0f / D_) - mean * mean;
        const float rstd = rsqrtf(var + LN_EPS);

        float cp = 0.f;
        #pragma unroll
        for (int k = 0; k < 8; ++k) {
            const int d = t + k * 256;
            const float nv = (vals[k] - mean) * rstd * rw_w[(size_t)r * D_ + d]
                           + rw_b[(size_t)r * D_ + d];
            Bt[(size_t)j * D_ + d] = f2bf(ln_w[(size_t)r * D_ + d] * nv);
            cp += ln_b[(size_t)r * D_ + d] * nv;
        }
        __syncthreads();   // sm reuse
        #pragma unroll
        for (int o = 32; o > 0; o >>= 1) cp += __shfl_xor(cp, o, 64);
        if ((t & 63) == 0) sm[t >> 6] = cp;
        __syncthreads();
        if (t == 0) cvec[j] = sm[0] + sm[1] + sm[2] + sm[3] + rbias[(size_t)r * A_ + a];
    }
}

// ---------------------------------------------------------------------------
// k_fused (R15): R7/R8 winning interleave + BK=64 + T2 XOR-swizzle.
//   decode r = bid&7 (router == XCD: Bt[r] L2-resident), mt = bid>>3.
//   BK=64 -> 32 iterations (HALF the barrier drains), 16 MFMA/stage.
//   LDS rows are 128 B = 8 x 16B slots; data for k-chunk kc of row lives at
//   slot kc ^ (row&7) (rule 21: swizzle the global SOURCE — a permutation
//   within each 128 B row segment, coalescing unchanged — and the READ addr;
//   global_load_lds dest stays linear). Fragment ds_read_b128: rows 0..7 hit
//   8 distinct slots -> conflict-free (was ~8-way at BK=32's 64 B rows).
//   NT stores kept (R9: plain stores thrash L2/L3, +44 us).
// ---------------------------------------------------------------------------
__global__ __launch_bounds__(256) void k_fused(
    const ushort* __restrict__ Xh,
    const ushort* __restrict__ Bt,
    const float* __restrict__ cvec,
    const float* __restrict__ ln_w,
    const float* __restrict__ ln_b,
    float* __restrict__ new_x,
    float* __restrict__ logits,
    float* __restrict__ probs)
{
    __shared__ __attribute__((aligned(16))) ushort As[64 * 64];    // 8 KB
    __shared__ __attribute__((aligned(16))) ushort Bs[128 * 64];   // 16 KB
    __shared__ __attribute__((aligned(16))) ushort lwS[D_];        // 4 KB
    __shared__ __attribute__((aligned(16))) ushort lbS[D_];        // 4 KB

    const int t    = threadIdx.x;
    const int lane = t & 63;
    const int w    = t >> 6;             // wave 0..3, rows w*16..w*16+15
    const int r    = blockIdx.x & 7;     // router == XCD
    const int mt   = blockIdx.x >> 3;    // m-tile 0..127
    const int m0   = mt * 64;
    const int j0   = r * 128;

    // LN params as bf16 (gamma=1/beta=0: bf16-exact); 8 ushorts per thread
    {
        const float4 wa = ((const float4*)(ln_w + (size_t)r * D_))[2 * t];
        const float4 wb = ((const float4*)(ln_w + (size_t)r * D_))[2 * t + 1];
        const float4 ba = ((const float4*)(ln_b + (size_t)r * D_))[2 * t];
        const float4 bb = ((const float4*)(ln_b + (size_t)r * D_))[2 * t + 1];
        *(ushort4*)(&lwS[t * 8])     = make_ushort4(f2bf(wa.x), f2bf(wa.y), f2bf(wa.z), f2bf(wa.w));
        *(ushort4*)(&lwS[t * 8 + 4]) = make_ushort4(f2bf(wb.x), f2bf(wb.y), f2bf(wb.z), f2bf(wb.w));
        *(ushort4*)(&lbS[t * 8])     = make_ushort4(f2bf(ba.x), f2bf(ba.y), f2bf(ba.z), f2bf(ba.w));
        *(ushort4*)(&lbS[t * 8 + 4]) = make_ushort4(f2bf(bb.x), f2bf(bb.y), f2bf(bb.z), f2bf(bb.w));
    }

    f32x4 acc[8];
    #pragma unroll
    for (int jf = 0; jf < 8; ++jf) acc[jf] = (f32x4){0.f, 0.f, 0.f, 0.f};

    float* nx_base = new_x + ((size_t)r * N_ + m0) * D_;

    for (int kt = 0; kt < 32; ++kt) {
        __syncthreads();                 // prev iter's LDS reads done
        // stage A: 512 chunks (2/thread); LDS pos (row,slot) <- global kc=slot^(row&7)
        #pragma unroll
        for (int c = 0; c < 2; ++c) {
            const int q    = t + c * 256;    // 0..511
            const int row  = q >> 3;         // 0..63
            const int slot = q & 7;
            const int kc   = slot ^ (row & 7);
            const ushort* gA = Xh + (size_t)(m0 + row) * D_ + kt * 64 + kc * 8;
            __builtin_amdgcn_global_load_lds(
                (const __attribute__((address_space(1))) void*)gA,
                (__attribute__((address_space(3))) void*)(&As[q * 8]), 16, 0, 0);
        }
        // stage B: 1024 chunks (4/thread)
        #pragma unroll
        for (int c = 0; c < 4; ++c) {
            const int q    = t + c * 256;    // 0..1023
            const int row  = q >> 3;         // 0..127
            const int slot = q & 7;
            const int kc   = slot ^ (row & 7);
            const ushort* gB = Bt + (size_t)(j0 + row) * D_ + kt * 64 + kc * 8;
            __builtin_amdgcn_global_load_lds(
                (const __attribute__((address_space(1))) void*)gB,
                (__attribute__((address_space(3))) void*)(&Bs[q * 8]), 16, 0, 0);
        }
        __syncthreads();                 // staging complete

        // new_x slab: 64 rows x 64 cols fp32; 4 NT f32x4 per thread.
        const int kbase = kt * 64;
        #pragma unroll
        for (int c = 0; c < 4; ++c) {
            const int q     = t + c * 256;   // 0..1023
            const int row   = q >> 4;        // 0..63
            const int c4    = q & 15;        // 4-float group within 64 cols
            const int pslot = (c4 >> 1) ^ (row & 7);
            const ushort4 hb = *(const ushort4*)(&As[row * 64 + pslot * 8 + (c4 & 1) * 4]);
            const int d = kbase + c4 * 4;
            const ushort4 w4 = *(const ushort4*)(&lwS[d]);
            const ushort4 b4 = *(const ushort4*)(&lbS[d]);
            f32x4 o;
            o[0] = bf2f(hb.x) * bf2f(w4.x) + bf2f(b4.x);
            o[1] = bf2f(hb.y) * bf2f(w4.y) + bf2f(b4.y);
            o[2] = bf2f(hb.z) * bf2f(w4.z) + bf2f(b4.z);
            o[3] = bf2f(hb.w) * bf2f(w4.w) + bf2f(b4.w);
            __builtin_nontemporal_store(o, (f32x4*)(nx_base + (size_t)row * D_ + d));
        }

        // MFMA: wave w rows w*16..+15; 2 k-frags x 8 j-frags, swizzled reads
        #pragma unroll
        for (int kf = 0; kf < 2; ++kf) {
            const int slot  = (lane >> 4) + 4 * kf;
            const int pslot = slot ^ (lane & 7);     // row&7 == lane&7 here
            const bf16x8 afr = *(const bf16x8*)(&As[(w * 16 + (lane & 15)) * 64
                                                    + pslot * 8]);
            #pragma unroll
            for (int jf = 0; jf < 8; ++jf) {
                const bf16x8 bfr = *(const bf16x8*)(&Bs[(jf * 16 + (lane & 15)) * 64
                                                        + pslot * 8]);
                acc[jf] = __builtin_amdgcn_mfma_f32_16x16x32_bf16(afr, bfr, acc[jf], 0, 0, 0);
            }
        }
    }

    // Epilogue: bias + row softmax (j-range == router r's full A=128).
    // C/D layout: col = lane&15, row = (lane>>4)*4 + reg.
    float cv[8];
    #pragma unroll
    for (int jf = 0; jf < 8; ++jf) cv[jf] = cvec[j0 + jf * 16 + (lane & 15)];

    #pragma unroll
    for (int reg = 0; reg < 4; ++reg) {
        const int row = m0 + w * 16 + (lane >> 4) * 4 + reg;
        float v[8], e[8];
        float mx = -3.4e38f;
        #pragma unroll
        for (int jf = 0; jf < 8; ++jf) {
            v[jf] = acc[jf][reg] + cv[jf];
            mx = fmaxf(mx, v[jf]);
        }
        #pragma unroll
        for (int o = 8; o > 0; o >>= 1) mx = fmaxf(mx, __shfl_xor(mx, o, 64));
        float ssum = 0.f;
        #pragma unroll
        for (int jf = 0; jf < 8; ++jf) { e[jf] = __expf(v[jf] - mx); ssum += e[jf]; }
        #pragma unroll
        for (int o = 8; o > 0; o >>= 1) ssum += __shfl_xor(ssum, o, 64);
        const float inv = 1.0f / ssum;
        float* lrow = logits + ((size_t)r * N_ + row) * A_;
        float* prow = probs  + ((size_t)r * N_ + row) * A_;
        #pragma unroll
        for (int jf = 0; jf < 8; ++jf) {
            const int aa = jf * 16 + (lane & 15);
            __builtin_nontemporal_store(v[jf], lrow + aa);
            __builtin_nontemporal_store(e[jf] * inv, prow + aa);
        }
    }
}

// ---------------------------------------------------------------------------
extern "C" void kernel_launch(void* const* d_in, const int* in_sizes, int n_in,
                              void* d_out, int out_size, void* d_ws, size_t ws_size,
                              hipStream_t stream)
{
    const float* x     = (const float*)d_in[0];
    const float* ln_w  = (const float*)d_in[1];
    const float* ln_b  = (const float*)d_in[2];
    const float* W     = (const float*)d_in[3];
    const float* rw_w  = (const float*)d_in[4];
    const float* rw_b  = (const float*)d_in[5];
    const float* rbias = (const float*)d_in[6];

    float* out    = (float*)d_out;
    float* new_x  = out;                                   // [R,N,D]
    float* logits = out + (size_t)R_ * N_ * D_;            // [R,N,A]
    float* probs  = logits + (size_t)R_ * N_ * A_;         // [R,N,A]

    // ws: xhat bf16 [N][D] (32 MiB) | Bt bf16 [J][D] (4 MiB) | cvec f32 [J]
    ushort* xhat = (ushort*)d_ws;
    ushort* Btp  = (ushort*)((char*)d_ws + (size_t)N_ * D_ * 2);
    float*  cvec = (float*)((char*)d_ws + (size_t)N_ * D_ * 2 + (size_t)J_ * D_ * 2);

    hipLaunchKernelGGL(k_prep, dim3(N_ + J_), dim3(256), 0, stream,
                       x, W, ln_w, ln_b, rw_w, rw_b, rbias, xhat, Btp, cvec);
    hipLaunchKernelGGL(k_fused, dim3(J_), dim3(256), 0, stream,
                       xhat, Btp, cvec, ln_w, ln_b, new_x, logits, probs);
}